// Round 1
// baseline (669.600 us; speedup 1.0000x reference)
//
#include <hip/hip_runtime.h>
#include <math.h>

#define NTOT 65536
#define CCH 128
#define LCH 512   // NTOT / CCH
#define SORT_BLOCKS 64

__device__ __forceinline__ float d_softplus(float x){
  return fmaxf(x, 0.f) + log1pf(__expf(-fabsf(x)));
}
__device__ __forceinline__ float d_sigmoid(float x){
  return 1.f / (1.f + __expf(-x));
}
__device__ __forceinline__ float fast_rcp(float x){
  return __builtin_amdgcn_rcpf(x);
}

// ---------------- sort: stable LSD radix on bits of |g| ----------------
__global__ void k_init_keys(const float* __restrict__ g, unsigned* __restrict__ keys,
                            unsigned* __restrict__ idx){
  int i = blockIdx.x*256 + threadIdx.x;
  keys[i] = __float_as_uint(g[i]) & 0x7fffffffu;
  idx[i] = (unsigned)i;
}

__global__ void k_hist(const unsigned* __restrict__ keys, unsigned* __restrict__ ghist, int shift){
  __shared__ unsigned h[256];
  int t = threadIdx.x;
  h[t] = 0u;
  __syncthreads();
  int base = blockIdx.x*1024;
  for (int r = 0; r < 4; ++r){
    unsigned d = (keys[base + r*256 + t] >> shift) & 255u;
    atomicAdd(&h[d], 1u);
  }
  __syncthreads();
  ghist[t*SORT_BLOCKS + blockIdx.x] = h[t];   // digit-major
}

__global__ void k_scan(unsigned* __restrict__ ghist){
  __shared__ unsigned part[256];
  int t = threadIdx.x;
  unsigned s = 0;
  for (int k = 0; k < SORT_BLOCKS; ++k) s += ghist[t*SORT_BLOCKS + k];
  part[t] = s;
  __syncthreads();
  for (int off = 1; off < 256; off <<= 1){
    unsigned v = (t >= off) ? part[t-off] : 0u;
    __syncthreads();
    part[t] += v;
    __syncthreads();
  }
  unsigned run = part[t] - s;   // exclusive prefix of thread totals
  for (int k = 0; k < SORT_BLOCKS; ++k){
    unsigned v = ghist[t*SORT_BLOCKS + k];
    ghist[t*SORT_BLOCKS + k] = run;
    run += v;
  }
}

__global__ __launch_bounds__(64) void k_scatter(const unsigned* __restrict__ keys_in,
                const unsigned* __restrict__ idx_in,
                unsigned* __restrict__ keys_out, unsigned* __restrict__ idx_out,
                const unsigned* __restrict__ goffs, int shift){
  __shared__ unsigned run[256];
  int lane = threadIdx.x;
  for (int k = lane; k < 256; k += 64) run[k] = goffs[k*SORT_BLOCKS + blockIdx.x];
  __syncthreads();
  int base = blockIdx.x*1024;
  for (int r = 0; r < 16; ++r){
    unsigned key = keys_in[base + r*64 + lane];
    unsigned id  = idx_in [base + r*64 + lane];
    unsigned dig = (key >> shift) & 255u;
    unsigned long long m = ~0ull;
    #pragma unroll
    for (int b = 0; b < 8; ++b){
      unsigned long long bb = __ballot((dig >> b) & 1u);
      m &= ((dig >> b) & 1u) ? bb : ~bb;
    }
    unsigned rank = (unsigned)__popcll(m & ((1ull << lane) - 1ull));
    unsigned cnt  = (unsigned)__popcll(m);
    unsigned pos = run[dig] + rank;
    if (rank == 0) run[dig] += cnt;     // one writer per digit, wave-ordered
    keys_out[pos] = key;
    idx_out[pos]  = id;
  }
}

__global__ void k_unsort(const unsigned* __restrict__ sidx, unsigned* __restrict__ unsrt){
  int j = blockIdx.x*256 + threadIdx.x;
  unsrt[sidx[j]] = (unsigned)j;
}

// ---------------- stage X: per-sorted-position precompute ----------------
__global__ void k_stagex(const float* __restrict__ g, const float* __restrict__ sh,
    const unsigned* __restrict__ sidx,
    const float* __restrict__ inprojW, const float* __restrict__ inprojb,
    const float* __restrict__ m_inW, const float* __restrict__ m_dtW,
    const float* __restrict__ m_dtb, const float* __restrict__ m_BW,
    const float* __restrict__ m_CW,
    float* __restrict__ DT, float* __restrict__ DXB, float* __restrict__ BA,
    float* __restrict__ CA, float* __restrict__ SZ, float* __restrict__ XB)
{
  __shared__ float w_in[512], w_dt[512], w_B[512], w_C[512], w_dtb[32], w_ip[16], w_ipb[8];
  int t = threadIdx.x;
  for (int k = t; k < 512; k += 256){ w_in[k]=m_inW[k]; w_dt[k]=m_dtW[k]; w_B[k]=m_BW[k]; w_C[k]=m_CW[k]; }
  if (t < 32) w_dtb[t] = m_dtb[t];
  if (t < 16) w_ip[t]  = inprojW[t];
  if (t < 8)  w_ipb[t] = inprojb[t];
  __syncthreads();
  int j = blockIdx.x*256 + t;
  unsigned i = sidx[j];
  float gj = g[i], sj = sh[i];
  float x[8];
  #pragma unroll
  for (int m = 0; m < 8; ++m) x[m] = w_ip[m*2]*gj + w_ip[m*2+1]*sj + w_ipb[m];
  for (int dir = 0; dir < 2; ++dir){
    const float* inW = &w_in[dir*256];
    float xb[16], z[16];
    #pragma unroll
    for (int k = 0; k < 16; ++k){
      float a = 0.f, b = 0.f;
      #pragma unroll
      for (int m = 0; m < 8; ++m){ a += inW[k*8+m]*x[m]; b += inW[(16+k)*8+m]*x[m]; }
      xb[k] = a; z[k] = b;
    }
    const float* dtW = &w_dt[dir*256];
    const float* BW  = &w_B[dir*256];
    const float* CW  = &w_C[dir*256];
    int base = (dir*NTOT + j)*16;
    #pragma unroll
    for (int k = 0; k < 16; ++k){
      float u = w_dtb[dir*16+k];
      #pragma unroll
      for (int m = 0; m < 16; ++m) u += dtW[k*16+m]*xb[m];
      float dt = d_softplus(u);
      DT [base+k] = dt;
      DXB[base+k] = dt*xb[k];
      float zz = z[k];
      SZ[base+k] = zz * d_sigmoid(zz);
      XB[base+k] = xb[k];
      float bb = 0.f, cc = 0.f;
      #pragma unroll
      for (int m = 0; m < 16; ++m){ bb += BW[k*16+m]*xb[m]; cc += CW[k*16+m]*xb[m]; }
      BA[base+k] = bb;
      CA[base+k] = cc;
    }
  }
}

// ---------------- phase A: per-chunk propagator P (16x16/channel) + bias q ----------------
__global__ __launch_bounds__(256) void k_phaseA(
    const float* __restrict__ DT, const float* __restrict__ DXB, const float* __restrict__ BA,
    const float* __restrict__ Alog, const float* __restrict__ rope,
    float* __restrict__ Parr, float* __restrict__ qarr)
{
  int chunk = blockIdx.x, dir = blockIdx.y;
  int t = threadIdx.x, d = t >> 4, s = t & 15;
  int lane = t & 63;
  int src = (lane & 48) | ((s + 15) & 15);
  float A  = -__expf(Alog[dir*256 + d*16 + s]);
  float rp = rope[dir*256 + d*16 + s];
  float P[16];
  #pragma unroll
  for (int c = 0; c < 16; ++c) P[c] = (c == s) ? 1.f : 0.f;
  float q = 0.f;
  const float* DTp = DT  + dir*NTOT*16;
  const float* DXp = DXB + dir*NTOT*16;
  const float* BAp = BA  + dir*NTOT*16;
  int stride = dir ? -16 : 16;
  int idx = (dir ? (NTOT - 1 - chunk*LCH) : chunk*LCH) * 16;
  for (int tt = 0; tt < LCH; ++tt, idx += stride){
    float dt  = DTp[idx + d];
    float dxb = DXp[idx + d];
    float Bs  = BAp[idx + s];
    float xh = dt * A * 0.5f;
    float Ab = (1.f + xh) * fast_rcp(1.f - xh + 1e-8f);
    float ph = dt * rp;
    float a = Ab * __cosf(ph);
    float b = -Ab * __sinf(ph);
    float qm = __shfl(q, src, 64);
    q = a*q + b*qm + dxb*Bs;
    #pragma unroll
    for (int c = 0; c < 16; ++c){
      float pm = __shfl(P[c], src, 64);
      P[c] = a*P[c] + b*pm;
    }
  }
  float* Pb = Parr + ((size_t)(dir*CCH + chunk)*256 + t)*16;
  #pragma unroll
  for (int c = 0; c < 16; ++c) Pb[c] = P[c];
  qarr[(dir*CCH + chunk)*256 + t] = q;
}

// ---------------- phase B: sequential combine over chunks (2 blocks) ----------------
__global__ __launch_bounds__(256) void k_phaseB(
    const float* __restrict__ Parr, const float* __restrict__ qarr,
    const float* __restrict__ mfwd, const float* __restrict__ mbwd,
    float* __restrict__ Sarr, float* __restrict__ dout)
{
  int dir = blockIdx.x;
  int t = threadIdx.x, lane = t & 63;
  float h = dir ? mbwd[t] : mfwd[t];
  float Pr[4][16]; float qr[4];
  #pragma unroll
  for (int w = 0; w < 4; ++w){
    const float* Pb = Parr + ((size_t)(dir*CCH + w)*256 + t)*16;
    #pragma unroll
    for (int c = 0; c < 16; ++c) Pr[w][c] = Pb[c];
    qr[w] = qarr[(dir*CCH + w)*256 + t];
  }
  for (int k = 0; k < CCH; k += 4){
    #pragma unroll
    for (int w = 0; w < 4; ++w){
      int kk = k + w;
      Sarr[(dir*CCH + kk)*256 + t] = h;
      float nh = qr[w];
      #pragma unroll
      for (int c = 0; c < 16; ++c){
        float hc = __shfl(h, (lane & 48) | c, 64);
        nh += Pr[w][c]*hc;
      }
      int kn = kk + 4;
      if (kn < CCH){
        const float* Pb = Parr + ((size_t)(dir*CCH + kn)*256 + t)*16;
        #pragma unroll
        for (int c = 0; c < 16; ++c) Pr[w][c] = Pb[c];
        qr[w] = qarr[(dir*CCH + kn)*256 + t];
      }
      h = nh;
    }
  }
  dout[5*NTOT + dir*256 + t] = h;   // new_fwd / new_bwd
}

// ---------------- phase C: per-chunk rescan with true start state, emit y ----------------
__global__ __launch_bounds__(256) void k_phaseC(
    const float* __restrict__ DT, const float* __restrict__ DXB,
    const float* __restrict__ BA, const float* __restrict__ CA,
    const float* __restrict__ Alog, const float* __restrict__ rope,
    const float* __restrict__ Sarr, float* __restrict__ Y)
{
  int chunk = blockIdx.x, dir = blockIdx.y;
  int t = threadIdx.x, d = t >> 4, s = t & 15;
  int lane = t & 63;
  int src = (lane & 48) | ((s + 15) & 15);
  float A  = -__expf(Alog[dir*256 + d*16 + s]);
  float rp = rope[dir*256 + d*16 + s];
  float h = Sarr[(dir*CCH + chunk)*256 + t];
  const float* DTp = DT  + dir*NTOT*16;
  const float* DXp = DXB + dir*NTOT*16;
  const float* BAp = BA  + dir*NTOT*16;
  const float* CAp = CA  + dir*NTOT*16;
  float* Yp = Y + dir*NTOT*16;
  int stride = dir ? -16 : 16;
  int idx = (dir ? (NTOT - 1 - chunk*LCH) : chunk*LCH) * 16;
  for (int tt = 0; tt < LCH; ++tt, idx += stride){
    float dt  = DTp[idx + d];
    float dxb = DXp[idx + d];
    float Bs  = BAp[idx + s];
    float Cs  = CAp[idx + s];
    float xh = dt * A * 0.5f;
    float Ab = (1.f + xh) * fast_rcp(1.f - xh + 1e-8f);
    float ph = dt * rp;
    float a = Ab * __cosf(ph);
    float b = -Ab * __sinf(ph);
    float hm = __shfl(h, src, 64);
    h = a*h + b*hm + dxb*Bs;
    float v = h * Cs;
    v += __shfl_xor(v, 1, 64);
    v += __shfl_xor(v, 2, 64);
    v += __shfl_xor(v, 4, 64);
    v += __shfl_xor(v, 8, 64);
    if (s == 0) Yp[idx + d] = v;
  }
}

// ---------------- ctx: y -> out projection per sorted position ----------------
__global__ void k_ctx(const float* __restrict__ Y, const float* __restrict__ SZ,
                      const float* __restrict__ XB, const float* __restrict__ m_D,
                      const float* __restrict__ m_outW, float* __restrict__ CTX)
{
  __shared__ float wD[32], wO[256];
  int t = threadIdx.x;
  if (t < 32) wD[t] = m_D[t];
  wO[t] = m_outW[t];
  __syncthreads();
  int j = blockIdx.x*256 + t;
  for (int dir = 0; dir < 2; ++dir){
    int base = (dir*NTOT + j)*16;
    float v[16];
    #pragma unroll
    for (int k = 0; k < 16; ++k)
      v[k] = Y[base+k]*SZ[base+k] + wD[dir*16+k]*XB[base+k];
    #pragma unroll
    for (int m = 0; m < 8; ++m){
      float a = 0.f;
      #pragma unroll
      for (int k = 0; k < 16; ++k) a += wO[dir*128 + m*16 + k]*v[k];
      CTX[(dir*NTOT + j)*8 + m] = a;
    }
  }
}

// ---------------- final: GRU + PEER per original element ----------------
__global__ __launch_bounds__(256) void k_final(
    const float* __restrict__ g, const float* __restrict__ sh,
    const float* __restrict__ gru_state, const unsigned* __restrict__ unsrt,
    const float* __restrict__ CTX,
    const float* __restrict__ Wz, const float* __restrict__ bz,
    const float* __restrict__ Wr, const float* __restrict__ br,
    const float* __restrict__ Wh, const float* __restrict__ bh,
    const float* __restrict__ qW, const float* __restrict__ kA, const float* __restrict__ kB,
    const float* __restrict__ eW1, const float* __restrict__ eb1,
    const float* __restrict__ eW2, const float* __restrict__ eb2,
    float* __restrict__ dout)
{
  __shared__ float sWz[88], sWr[88], sWh[88], sbz[4], sbr[4], sbh[4];
  __shared__ float sqW[704], skA[192], skB[192];
  __shared__ float sW1[2304], sb1[2304], sW2[2304], sb2[144];
  int t = threadIdx.x;
  for (int k = t; k < 88; k += 256){ sWz[k]=Wz[k]; sWr[k]=Wr[k]; sWh[k]=Wh[k]; }
  if (t < 4){ sbz[t]=bz[t]; sbr[t]=br[t]; sbh[t]=bh[t]; }
  for (int k = t; k < 704; k += 256) sqW[k]=qW[k];
  for (int k = t; k < 192; k += 256){ skA[k]=kA[k]; skB[k]=kB[k]; }
  for (int k = t; k < 2304; k += 256){ sW1[k]=eW1[k]; sb1[k]=eb1[k]; sW2[k]=eW2[k]; }
  for (int k = t; k < 144; k += 256) sb2[k]=eb2[k];
  __syncthreads();
  int i = blockIdx.x*256 + t;
  float gi = g[i], si = sh[i];
  unsigned p = unsrt[i];
  float xin[22];
  xin[0] = gi; xin[1] = si;
  #pragma unroll
  for (int m = 0; m < 8; ++m){
    xin[2+m]  = CTX[p*8 + m];
    xin[10+m] = CTX[NTOT*8 + p*8 + m];
  }
  float h[4];
  #pragma unroll
  for (int k = 0; k < 4; ++k) h[k] = gru_state[i*4 + k];
  float zg[4], r[4];
  #pragma unroll
  for (int o = 0; o < 4; ++o){
    float az = sbz[o], ar = sbr[o];
    #pragma unroll
    for (int c = 0; c < 18; ++c){ az += sWz[o*22+c]*xin[c]; ar += sWr[o*22+c]*xin[c]; }
    #pragma unroll
    for (int c = 0; c < 4; ++c){ az += sWz[o*22+18+c]*h[c]; ar += sWr[o*22+18+c]*h[c]; }
    zg[o] = d_sigmoid(az);
    r[o]  = d_sigmoid(ar);
  }
  float ng[4];
  #pragma unroll
  for (int o = 0; o < 4; ++o){
    float ah = sbh[o];
    #pragma unroll
    for (int c = 0; c < 18; ++c) ah += sWh[o*22+c]*xin[c];
    #pragma unroll
    for (int c = 0; c < 4; ++c) ah += sWh[o*22+18+c]*(r[c]*h[c]);
    float ht = tanhf(ah);
    ng[o] = (1.f - zg[o])*h[o] + zg[o]*ht;
  }
  float pin[22];
  #pragma unroll
  for (int k = 0; k < 4; ++k) pin[k] = ng[k];
  #pragma unroll
  for (int m = 0; m < 16; ++m) pin[4+m] = xin[2+m];
  pin[20] = gi; pin[21] = si;
  float total = 0.f;
  #pragma unroll
  for (int hh = 0; hh < 4; ++hh){
    float qv[8];
    #pragma unroll
    for (int o = 0; o < 8; ++o){
      float a = 0.f;
      #pragma unroll
      for (int c = 0; c < 22; ++c) a += sqW[hh*176 + o*22 + c]*pin[c];
      qv[o] = a;
    }
    int ia = 0; float best = -1e30f;
    #pragma unroll
    for (int k = 0; k < 12; ++k){
      float sc = 0.f;
      #pragma unroll
      for (int m = 0; m < 4; ++m) sc += skA[hh*48 + k*4 + m]*qv[m];
      if (sc > best){ best = sc; ia = k; }
    }
    int ib = 0; best = -1e30f;
    #pragma unroll
    for (int k = 0; k < 12; ++k){
      float sc = 0.f;
      #pragma unroll
      for (int m = 0; m < 4; ++m) sc += skB[hh*48 + k*4 + m]*qv[4+m];
      if (sc > best){ best = sc; ib = k; }
    }
    int e = ia*12 + ib;
    float outv = sb2[e];
    #pragma unroll
    for (int u = 0; u < 16; ++u){
      float z1 = fmaxf(sW1[e*16+u]*gi + sb1[e*16+u], 0.f);
      outv += sW2[e*16+u]*z1;
    }
    total += outv;
  }
  total *= 0.25f;
  dout[i] = gi + 0.1f*total;
  #pragma unroll
  for (int k = 0; k < 4; ++k) dout[NTOT + i*4 + k] = ng[k];
}

extern "C" void kernel_launch(void* const* d_in, const int* in_sizes, int n_in,
                              void* d_out, int out_size, void* d_ws, size_t ws_size,
                              hipStream_t stream)
{
  const float* grad     = (const float*)d_in[0];
  const float* sharp    = (const float*)d_in[1];
  const float* gru_st   = (const float*)d_in[2];
  const float* mfwd     = (const float*)d_in[3];
  const float* mbwd     = (const float*)d_in[4];
  const float* inprojW  = (const float*)d_in[5];
  const float* inprojb  = (const float*)d_in[6];
  const float* m_inW    = (const float*)d_in[7];
  const float* m_dtW    = (const float*)d_in[8];
  const float* m_dtb    = (const float*)d_in[9];
  const float* m_BW     = (const float*)d_in[10];
  const float* m_CW     = (const float*)d_in[11];
  const float* m_Alog   = (const float*)d_in[12];
  const float* m_D      = (const float*)d_in[13];
  const float* m_rope   = (const float*)d_in[14];
  const float* m_outW   = (const float*)d_in[15];
  const float* gWz      = (const float*)d_in[16];
  const float* gbz      = (const float*)d_in[17];
  const float* gWr      = (const float*)d_in[18];
  const float* gbr      = (const float*)d_in[19];
  const float* gWh      = (const float*)d_in[20];
  const float* gbh      = (const float*)d_in[21];
  const float* peer_qW  = (const float*)d_in[22];
  const float* keysA    = (const float*)d_in[23];
  const float* keysB    = (const float*)d_in[24];
  const float* eW1      = (const float*)d_in[25];
  const float* eb1      = (const float*)d_in[26];
  const float* eW2      = (const float*)d_in[27];
  const float* eb2      = (const float*)d_in[28];
  float* out = (float*)d_out;

  char* base = (char*)d_ws;
  size_t off = 0;
  auto alloc = [&](size_t bytes)->void*{
    void* p = (void*)(base + off);
    off = (off + bytes + 255) & ~(size_t)255;
    return p;
  };
  unsigned* keys0 = (unsigned*)alloc((size_t)NTOT*4);
  unsigned* keys1 = (unsigned*)alloc((size_t)NTOT*4);
  unsigned* idx0  = (unsigned*)alloc((size_t)NTOT*4);
  unsigned* idx1  = (unsigned*)alloc((size_t)NTOT*4);
  unsigned* ghist = (unsigned*)alloc((size_t)256*SORT_BLOCKS*4);
  unsigned* unsrt = (unsigned*)alloc((size_t)NTOT*4);
  float* DT   = (float*)alloc((size_t)2*NTOT*16*4);
  float* DXB  = (float*)alloc((size_t)2*NTOT*16*4);
  float* BA   = (float*)alloc((size_t)2*NTOT*16*4);
  float* CA   = (float*)alloc((size_t)2*NTOT*16*4);
  float* SZ   = (float*)alloc((size_t)2*NTOT*16*4);
  float* XBt  = (float*)alloc((size_t)2*NTOT*16*4);
  float* Yt   = (float*)alloc((size_t)2*NTOT*16*4);
  float* Parr = (float*)alloc((size_t)2*CCH*256*16*4);
  float* qarr = (float*)alloc((size_t)2*CCH*256*4);
  float* Sarr = (float*)alloc((size_t)2*CCH*256*4);
  float* CTX  = (float*)alloc((size_t)2*NTOT*8*4);

  k_init_keys<<<NTOT/256, 256, 0, stream>>>(grad, keys0, idx0);
  unsigned *ka = keys0, *kb = keys1, *ia = idx0, *ib = idx1;
  for (int p = 0; p < 4; ++p){
    k_hist   <<<SORT_BLOCKS, 256, 0, stream>>>(ka, ghist, p*8);
    k_scan   <<<1, 256, 0, stream>>>(ghist);
    k_scatter<<<SORT_BLOCKS, 64, 0, stream>>>(ka, ia, kb, ib, ghist, p*8);
    unsigned* tk = ka; ka = kb; kb = tk;
    unsigned* ti = ia; ia = ib; ib = ti;
  }
  k_unsort<<<NTOT/256, 256, 0, stream>>>(ia, unsrt);
  k_stagex<<<NTOT/256, 256, 0, stream>>>(grad, sharp, ia, inprojW, inprojb,
      m_inW, m_dtW, m_dtb, m_BW, m_CW, DT, DXB, BA, CA, SZ, XBt);
  k_phaseA<<<dim3(CCH,2), 256, 0, stream>>>(DT, DXB, BA, m_Alog, m_rope, Parr, qarr);
  k_phaseB<<<2, 256, 0, stream>>>(Parr, qarr, mfwd, mbwd, Sarr, out);
  k_phaseC<<<dim3(CCH,2), 256, 0, stream>>>(DT, DXB, BA, CA, m_Alog, m_rope, Sarr, Yt);
  k_ctx<<<NTOT/256, 256, 0, stream>>>(Yt, SZ, XBt, m_D, m_outW, CTX);
  k_final<<<NTOT/256, 256, 0, stream>>>(grad, sharp, gru_st, unsrt, CTX,
      gWz, gbz, gWr, gbr, gWh, gbh, peer_qW, keysA, keysB, eW1, eb1, eW2, eb2, out);
}

// Round 2
// 394.314 us; speedup vs baseline: 1.6981x; 1.6981x over previous
//
#include <hip/hip_runtime.h>
#include <math.h>

#define NTOT 65536
#define LCH 256
#define WRM 256
#define CCH 256          // NTOT / LCH
#define SORT_BLOCKS 256

__device__ __forceinline__ float d_softplus(float x){
  return fmaxf(x, 0.f) + log1pf(__expf(-fabsf(x)));
}
__device__ __forceinline__ float d_sigmoid(float x){
  return 1.f / (1.f + __expf(-x));
}
__device__ __forceinline__ float fast_rcp(float x){
  return __builtin_amdgcn_rcpf(x);
}
template<int CTRL>
__device__ __forceinline__ float dpp_mov(float x){
  return __int_as_float(__builtin_amdgcn_update_dpp(0, __float_as_int(x), CTRL, 0xF, 0xF, true));
}
// DPP ctrls: quad_perm [1,0,3,2] = 0xB1 (xor1), [2,3,0,1] = 0x4E (xor2),
// row_ror:1 = 0x121 (lane i <- lane (i-1)&15), row_mirror = 0x140, row_half_mirror = 0x141.

// ---------------- sort: stable LSD radix on bits of |g| ----------------
__global__ void k_init_keys(const float* __restrict__ g, unsigned* __restrict__ keys,
                            unsigned* __restrict__ idx){
  int i = blockIdx.x*256 + threadIdx.x;
  keys[i] = __float_as_uint(g[i]) & 0x7fffffffu;
  idx[i] = (unsigned)i;
}

__global__ void k_hist(const unsigned* __restrict__ keys, unsigned* __restrict__ ghist, int shift){
  __shared__ unsigned h[256];
  int t = threadIdx.x;
  h[t] = 0u;
  __syncthreads();
  unsigned d = (keys[blockIdx.x*256 + t] >> shift) & 255u;
  atomicAdd(&h[d], 1u);
  __syncthreads();
  ghist[t*SORT_BLOCKS + blockIdx.x] = h[t];   // digit-major
}

__global__ void k_scan(unsigned* __restrict__ ghist){
  __shared__ unsigned part[256];
  int t = threadIdx.x;
  unsigned s = 0;
  for (int k = 0; k < SORT_BLOCKS; ++k) s += ghist[t*SORT_BLOCKS + k];
  part[t] = s;
  __syncthreads();
  for (int off = 1; off < 256; off <<= 1){
    unsigned v = (t >= off) ? part[t-off] : 0u;
    __syncthreads();
    part[t] += v;
    __syncthreads();
  }
  unsigned run = part[t] - s;   // exclusive prefix of digit totals
  for (int k = 0; k < SORT_BLOCKS; ++k){
    unsigned v = ghist[t*SORT_BLOCKS + k];
    ghist[t*SORT_BLOCKS + k] = run;
    run += v;
  }
}

__global__ __launch_bounds__(64) void k_scatter(const unsigned* __restrict__ keys_in,
                const unsigned* __restrict__ idx_in,
                unsigned* __restrict__ keys_out, unsigned* __restrict__ idx_out,
                const unsigned* __restrict__ goffs, int shift){
  __shared__ unsigned run[256];
  int lane = threadIdx.x;
  for (int k = lane; k < 256; k += 64) run[k] = goffs[k*SORT_BLOCKS + blockIdx.x];
  __syncthreads();
  int base = blockIdx.x*256;
  for (int r = 0; r < 4; ++r){
    unsigned key = keys_in[base + r*64 + lane];
    unsigned id  = idx_in [base + r*64 + lane];
    unsigned dig = (key >> shift) & 255u;
    unsigned long long m = ~0ull;
    #pragma unroll
    for (int b = 0; b < 8; ++b){
      unsigned long long bb = __ballot((dig >> b) & 1u);
      m &= ((dig >> b) & 1u) ? bb : ~bb;
    }
    unsigned rank = (unsigned)__popcll(m & ((1ull << lane) - 1ull));
    unsigned cnt  = (unsigned)__popcll(m);
    unsigned pos = run[dig] + rank;
    if (rank == 0) run[dig] += cnt;     // one writer per digit, wave-ordered
    keys_out[pos] = key;
    idx_out[pos]  = id;
  }
}

// ---------------- stage X: per-sorted-position precompute, packed STEP layout ----
// Per dir, per position pair (pair = j>>1, sub = j&1), 768 B = 192 floats:
//   d-block: [d*8 + sub*4] float4 {dt, dt*xb, sz, xb}   (16 d x 2 sub x 16B = 512 B)
//   s-block: [128 + s*4 + sub*2] float2 {ba, ca}        (16 s x 2 sub x 8B  = 256 B)
__global__ void k_stagex(const float* __restrict__ g, const float* __restrict__ sh,
    const unsigned* __restrict__ sidx,
    const float* __restrict__ inprojW, const float* __restrict__ inprojb,
    const float* __restrict__ m_inW, const float* __restrict__ m_dtW,
    const float* __restrict__ m_dtb, const float* __restrict__ m_BW,
    const float* __restrict__ m_CW,
    float* __restrict__ STEP)
{
  __shared__ float w_in[512], w_dt[512], w_B[512], w_C[512], w_dtb[32], w_ip[16], w_ipb[8];
  int t = threadIdx.x;
  for (int k = t; k < 512; k += 256){ w_in[k]=m_inW[k]; w_dt[k]=m_dtW[k]; w_B[k]=m_BW[k]; w_C[k]=m_CW[k]; }
  if (t < 32) w_dtb[t] = m_dtb[t];
  if (t < 16) w_ip[t]  = inprojW[t];
  if (t < 8)  w_ipb[t] = inprojb[t];
  __syncthreads();
  int j = blockIdx.x*256 + t;
  unsigned i = sidx[j];
  float gj = g[i], sj = sh[i];
  float x[8];
  #pragma unroll
  for (int m = 0; m < 8; ++m) x[m] = w_ip[m*2]*gj + w_ip[m*2+1]*sj + w_ipb[m];
  int pair = j >> 1, sub = j & 1;
  for (int dir = 0; dir < 2; ++dir){
    const float* inW = &w_in[dir*256];
    float xb[16], z[16];
    #pragma unroll
    for (int k = 0; k < 16; ++k){
      float a = 0.f, b = 0.f;
      #pragma unroll
      for (int m = 0; m < 8; ++m){ a += inW[k*8+m]*x[m]; b += inW[(16+k)*8+m]*x[m]; }
      xb[k] = a; z[k] = b;
    }
    const float* dtW = &w_dt[dir*256];
    const float* BW  = &w_B[dir*256];
    const float* CW  = &w_C[dir*256];
    float* base = STEP + (size_t)(dir*(NTOT/2) + pair)*192;
    #pragma unroll
    for (int k = 0; k < 16; ++k){
      float u = w_dtb[dir*16+k];
      #pragma unroll
      for (int m = 0; m < 16; ++m) u += dtW[k*16+m]*xb[m];
      float dt = d_softplus(u);
      float zz = z[k];
      float sz = zz * d_sigmoid(zz);
      *(float4*)(base + k*8 + sub*4) = make_float4(dt, dt*xb[k], sz, xb[k]);
      float bb = 0.f, cc = 0.f;
      #pragma unroll
      for (int m = 0; m < 16; ++m){ bb += BW[k*16+m]*xb[m]; cc += CW[k*16+m]*xb[m]; }
      *(float2*)(base + 128 + k*4 + sub*2) = make_float2(bb, cc);
    }
  }
}

// ---------------- fused scan: warm-up-from-zero chunked recurrence ----------------
// grid (CCH, 2). thread t: d = t>>4 (channel), s = t&15 (state).
// V[dir][pos][d] = y*silu(z) + D*xb  (pre-outW vector), final states -> dout tail.
__global__ __launch_bounds__(256) void k_scan_fused(
    const float* __restrict__ STEP, const float* __restrict__ Alog,
    const float* __restrict__ rope, const float* __restrict__ m_D,
    const float* __restrict__ mfwd, const float* __restrict__ mbwd,
    float* __restrict__ V, float* __restrict__ dout)
{
  __shared__ float lds[6144];   // 24 KB: one tile = 64 positions x 96 floats
  int c = blockIdx.x, dir = blockIdx.y;
  int t = threadIdx.x, d = t >> 4, s = t & 15;
  float Ah = -__expf(Alog[dir*256 + d*16 + s]) * 0.5f;
  float rp = rope[dir*256 + d*16 + s];
  float Dd = m_D[dir*16 + d];
  bool fwd = (dir == 0);
  int warm = ((fwd && c == 0) || (!fwd && c == CCH-1)) ? 0 : WRM;
  int T = (LCH + warm) >> 6;
  int warmT = warm >> 6;
  float h = (warm == 0) ? (fwd ? mfwd[t] : mbwd[t]) : 0.f;
  float* Vp = V + (size_t)dir*NTOT*16;
  const float* Sp = STEP + (size_t)dir*(NTOT/2)*192;

  float4 pf[6];
  // tile j low position
  #define TILELO(j) (fwd ? (c*LCH - warm + (j)*64) : ((c+1)*LCH + warm - ((j)+1)*64))
  {
    const float4* gp = (const float4*)(Sp + (size_t)(TILELO(0) >> 1)*192);
    #pragma unroll
    for (int k = 0; k < 6; ++k) pf[k] = gp[t + k*256];
  }
  for (int j = 0; j < T; ++j){
    if (j) __syncthreads();                       // all waves done reading previous tile
    #pragma unroll
    for (int k = 0; k < 6; ++k) ((float4*)lds)[t + k*256] = pf[k];
    __syncthreads();                              // tile visible
    if (j + 1 < T){
      const float4* gp = (const float4*)(Sp + (size_t)(TILELO(j+1) >> 1)*192);
      #pragma unroll
      for (int k = 0; k < 6; ++k) pf[k] = gp[t + k*256];
    }
    bool real = (j >= warmT);
    int lo = TILELO(j);
    for (int mb = 0; mb < 16; ++mb){
      float y0 = 0.f, y1 = 0.f, y2 = 0.f, y3 = 0.f;
      #pragma unroll
      for (int q = 0; q < 4; ++q){
        int m = mb*4 + q;
        int lm = fwd ? m : 63 - m;
        int pr = lm >> 1, sub = lm & 1;
        float4 dd = *(const float4*)&lds[pr*192 + d*8 + sub*4];
        float2 sv = *(const float2*)&lds[pr*192 + 128 + s*4 + sub*2];
        float dt = dd.x, dxb = dd.y;
        float xh = dt * Ah;
        float Ab = (1.f + xh) * fast_rcp(1.f - xh + 1e-8f);
        float ph = dt * rp;
        float a = Ab * __cosf(ph);
        float b = -Ab * __sinf(ph);
        float hm = dpp_mov<0x121>(h);             // roll(h,1): lane s <- s-1
        h = fmaf(a, h, fmaf(b, hm, dxb * sv.x));
        if (real){
          float v = h * sv.y;
          v += dpp_mov<0xB1>(v);                  // xor1
          v += dpp_mov<0x4E>(v);                  // xor2
          v += dpp_mov<0x140>(v);                 // quads q + 3-q
          v += dpp_mov<0x141>(v);                 // full 16-sum in all lanes
          float val = fmaf(v, dd.z, Dd * dd.w);   // y*sz + D*xb
          if (q == 0) y0 = val; else if (q == 1) y1 = val;
          else if (q == 2) y2 = val; else y3 = val;
        }
      }
      if (real && s < 4){
        float val = (s == 0) ? y0 : ((s == 1) ? y1 : ((s == 2) ? y2 : y3));
        int pos = fwd ? (lo + mb*4 + s) : (lo + 63 - mb*4 - s);
        Vp[pos*16 + d] = val;
      }
    }
  }
  #undef TILELO
  if ((fwd && c == CCH-1) || (!fwd && c == 0))
    dout[5*NTOT + dir*256 + t] = h;               // new_fwd / new_bwd
}

// ---------------- ctx: V -> outW projection, scattered to ORIGINAL order ----------
__global__ void k_ctx(const float* __restrict__ V, const unsigned* __restrict__ sidx,
                      const float* __restrict__ m_outW, float* __restrict__ CTX)
{
  __shared__ float wO[256];
  int t = threadIdx.x;
  wO[t] = m_outW[t];
  __syncthreads();
  int j = blockIdx.x*256 + t;
  unsigned i = sidx[j];
  for (int dir = 0; dir < 2; ++dir){
    const float* vp = V + (size_t)dir*NTOT*16 + (size_t)j*16;
    float v[16];
    #pragma unroll
    for (int k = 0; k < 4; ++k){
      float4 f = ((const float4*)vp)[k];
      v[k*4] = f.x; v[k*4+1] = f.y; v[k*4+2] = f.z; v[k*4+3] = f.w;
    }
    #pragma unroll
    for (int m = 0; m < 8; ++m){
      float a = 0.f;
      #pragma unroll
      for (int k = 0; k < 16; ++k) a += wO[dir*128 + m*16 + k]*v[k];
      CTX[(size_t)i*16 + dir*8 + m] = a;
    }
  }
}

// ---------------- final: GRU + PEER per original element (coalesced CTX) ----------
__global__ __launch_bounds__(256) void k_final(
    const float* __restrict__ g, const float* __restrict__ sh,
    const float* __restrict__ gru_state,
    const float* __restrict__ CTX,
    const float* __restrict__ Wz, const float* __restrict__ bz,
    const float* __restrict__ Wr, const float* __restrict__ br,
    const float* __restrict__ Wh, const float* __restrict__ bh,
    const float* __restrict__ qW, const float* __restrict__ kA, const float* __restrict__ kB,
    const float* __restrict__ eW1, const float* __restrict__ eb1,
    const float* __restrict__ eW2, const float* __restrict__ eb2,
    float* __restrict__ dout)
{
  __shared__ float sWz[88], sWr[88], sWh[88], sbz[4], sbr[4], sbh[4];
  __shared__ float sqW[704], skA[192], skB[192];
  __shared__ float sW1[2304], sb1[2304], sW2[2304], sb2[144];
  int t = threadIdx.x;
  for (int k = t; k < 88; k += 256){ sWz[k]=Wz[k]; sWr[k]=Wr[k]; sWh[k]=Wh[k]; }
  if (t < 4){ sbz[t]=bz[t]; sbr[t]=br[t]; sbh[t]=bh[t]; }
  for (int k = t; k < 704; k += 256) sqW[k]=qW[k];
  for (int k = t; k < 192; k += 256){ skA[k]=kA[k]; skB[k]=kB[k]; }
  for (int k = t; k < 2304; k += 256){ sW1[k]=eW1[k]; sb1[k]=eb1[k]; sW2[k]=eW2[k]; }
  for (int k = t; k < 144; k += 256) sb2[k]=eb2[k];
  __syncthreads();
  int i = blockIdx.x*256 + t;
  float gi = g[i], si = sh[i];
  float xin[22];
  xin[0] = gi; xin[1] = si;
  const float* cp = CTX + (size_t)i*16;
  #pragma unroll
  for (int m = 0; m < 8; ++m){
    xin[2+m]  = cp[m];
    xin[10+m] = cp[8+m];
  }
  float h[4];
  #pragma unroll
  for (int k = 0; k < 4; ++k) h[k] = gru_state[i*4 + k];
  float zg[4], r[4];
  #pragma unroll
  for (int o = 0; o < 4; ++o){
    float az = sbz[o], ar = sbr[o];
    #pragma unroll
    for (int c = 0; c < 18; ++c){ az += sWz[o*22+c]*xin[c]; ar += sWr[o*22+c]*xin[c]; }
    #pragma unroll
    for (int c = 0; c < 4; ++c){ az += sWz[o*22+18+c]*h[c]; ar += sWr[o*22+18+c]*h[c]; }
    zg[o] = d_sigmoid(az);
    r[o]  = d_sigmoid(ar);
  }
  float ng[4];
  #pragma unroll
  for (int o = 0; o < 4; ++o){
    float ah = sbh[o];
    #pragma unroll
    for (int c = 0; c < 18; ++c) ah += sWh[o*22+c]*xin[c];
    #pragma unroll
    for (int c = 0; c < 4; ++c) ah += sWh[o*22+18+c]*(r[c]*h[c]);
    float ht = tanhf(ah);
    ng[o] = (1.f - zg[o])*h[o] + zg[o]*ht;
  }
  float pin[22];
  #pragma unroll
  for (int k = 0; k < 4; ++k) pin[k] = ng[k];
  #pragma unroll
  for (int m = 0; m < 16; ++m) pin[4+m] = xin[2+m];
  pin[20] = gi; pin[21] = si;
  float total = 0.f;
  #pragma unroll
  for (int hh = 0; hh < 4; ++hh){
    float qv[8];
    #pragma unroll
    for (int o = 0; o < 8; ++o){
      float a = 0.f;
      #pragma unroll
      for (int c = 0; c < 22; ++c) a += sqW[hh*176 + o*22 + c]*pin[c];
      qv[o] = a;
    }
    int ia = 0; float best = -1e30f;
    #pragma unroll
    for (int k = 0; k < 12; ++k){
      float sc = 0.f;
      #pragma unroll
      for (int m = 0; m < 4; ++m) sc += skA[hh*48 + k*4 + m]*qv[m];
      if (sc > best){ best = sc; ia = k; }
    }
    int ib = 0; best = -1e30f;
    #pragma unroll
    for (int k = 0; k < 12; ++k){
      float sc = 0.f;
      #pragma unroll
      for (int m = 0; m < 4; ++m) sc += skB[hh*48 + k*4 + m]*qv[4+m];
      if (sc > best){ best = sc; ib = k; }
    }
    int e = ia*12 + ib;
    float outv = sb2[e];
    #pragma unroll
    for (int u = 0; u < 16; ++u){
      float z1 = fmaxf(sW1[e*16+u]*gi + sb1[e*16+u], 0.f);
      outv += sW2[e*16+u]*z1;
    }
    total += outv;
  }
  total *= 0.25f;
  dout[i] = gi + 0.1f*total;
  #pragma unroll
  for (int k = 0; k < 4; ++k) dout[NTOT + i*4 + k] = ng[k];
}

extern "C" void kernel_launch(void* const* d_in, const int* in_sizes, int n_in,
                              void* d_out, int out_size, void* d_ws, size_t ws_size,
                              hipStream_t stream)
{
  const float* grad     = (const float*)d_in[0];
  const float* sharp    = (const float*)d_in[1];
  const float* gru_st   = (const float*)d_in[2];
  const float* mfwd     = (const float*)d_in[3];
  const float* mbwd     = (const float*)d_in[4];
  const float* inprojW  = (const float*)d_in[5];
  const float* inprojb  = (const float*)d_in[6];
  const float* m_inW    = (const float*)d_in[7];
  const float* m_dtW    = (const float*)d_in[8];
  const float* m_dtb    = (const float*)d_in[9];
  const float* m_BW     = (const float*)d_in[10];
  const float* m_CW     = (const float*)d_in[11];
  const float* m_Alog   = (const float*)d_in[12];
  const float* m_D      = (const float*)d_in[13];
  const float* m_rope   = (const float*)d_in[14];
  const float* m_outW   = (const float*)d_in[15];
  const float* gWz      = (const float*)d_in[16];
  const float* gbz      = (const float*)d_in[17];
  const float* gWr      = (const float*)d_in[18];
  const float* gbr      = (const float*)d_in[19];
  const float* gWh      = (const float*)d_in[20];
  const float* gbh      = (const float*)d_in[21];
  const float* peer_qW  = (const float*)d_in[22];
  const float* keysA    = (const float*)d_in[23];
  const float* keysB    = (const float*)d_in[24];
  const float* eW1      = (const float*)d_in[25];
  const float* eb1      = (const float*)d_in[26];
  const float* eW2      = (const float*)d_in[27];
  const float* eb2      = (const float*)d_in[28];
  float* out = (float*)d_out;

  char* base = (char*)d_ws;
  size_t off = 0;
  auto alloc = [&](size_t bytes)->void*{
    void* p = (void*)(base + off);
    off = (off + bytes + 255) & ~(size_t)255;
    return p;
  };
  unsigned* keys0 = (unsigned*)alloc((size_t)NTOT*4);
  unsigned* keys1 = (unsigned*)alloc((size_t)NTOT*4);
  unsigned* idx0  = (unsigned*)alloc((size_t)NTOT*4);
  unsigned* idx1  = (unsigned*)alloc((size_t)NTOT*4);
  unsigned* ghist = (unsigned*)alloc((size_t)256*SORT_BLOCKS*4);
  float* STEP = (float*)alloc((size_t)2*(NTOT/2)*192*4);   // 50.3 MB
  float* V    = (float*)alloc((size_t)2*NTOT*16*4);        // 8 MB
  float* CTX  = (float*)alloc((size_t)NTOT*16*4);          // 4 MB

  k_init_keys<<<NTOT/256, 256, 0, stream>>>(grad, keys0, idx0);
  unsigned *ka = keys0, *kb = keys1, *ia = idx0, *ib = idx1;
  for (int p = 0; p < 4; ++p){
    k_hist   <<<SORT_BLOCKS, 256, 0, stream>>>(ka, ghist, p*8);
    k_scan   <<<1, 256, 0, stream>>>(ghist);
    k_scatter<<<SORT_BLOCKS, 64, 0, stream>>>(ka, ia, kb, ib, ghist, p*8);
    unsigned* tk = ka; ka = kb; kb = tk;
    unsigned* ti = ia; ia = ib; ib = ti;
  }
  k_stagex<<<NTOT/256, 256, 0, stream>>>(grad, sharp, ia, inprojW, inprojb,
      m_inW, m_dtW, m_dtb, m_BW, m_CW, STEP);
  k_scan_fused<<<dim3(CCH, 2), 256, 0, stream>>>(STEP, m_Alog, m_rope, m_D,
      mfwd, mbwd, V, out);
  k_ctx<<<NTOT/256, 256, 0, stream>>>(V, ia, m_outW, CTX);
  k_final<<<NTOT/256, 256, 0, stream>>>(grad, sharp, gru_st, CTX,
      gWz, gbz, gWr, gbr, gWh, gbh, peer_qW, keysA, keysB, eW1, eb1, eW2, eb2, out);
}